// Round 11
// baseline (198.531 us; speedup 1.0000x reference)
//
#include <hip/hip_runtime.h>

// CP-decomposed 3D conv (AirConv3D): B=1, Cin=32, Cout=64, 56^3, K=3, pad=1, rank=53.
// All-f32 (R1-R5). ws ~268 MB. Lessons: R9 — never block-split a reduction reader
// (traffic multiplies, no cross-XCD reuse); R10 — pipeline is achieved-BW x traffic
// bound (~1.5-2 TB/s at our occupancies vs 6 TB/s fills).
// R11: cut traffic 225->151 MB by deleting k2w; its w-conv folds into k3 as a
// 9-tap (w,h) stencil whose refetch overlap is L2-absorbed and whose 9
// independent loads/iter give 3x the MLP of R10's k3f2.
//   k0_t : Ucin^T -> Ut[r][c] in ws after T1
//   k1d  : pointwise 32->53 fused with d-conv via in-wave __shfl. T1d -> ws.
//   k3wh : 9-tap (kh x kw) stencil + 53->64 projection + bias. float2 lanes.
// Fallback (small ws): R5 pipeline (known good).

#define NP 175616   // 56*56*56
#define NP2 87808   // NP/2 float2 columns
#define HSTR 3136   // 56*56
#define H2 1568     // HSTR/2 float2 per h-plane
#define W2 28       // 56/2 float2 per w-row
#define CIN 32
#define RK 53
#define COUT 64
#define SCR 53      // fallback scratch slice base in d_out

// ---- k0: Ut[r*32+c] = Ucin[c*53+r] ----
__global__ __launch_bounds__(256) void k0_t(const float* __restrict__ Ucin,
                                            float* __restrict__ Ut)
{
    int t = blockIdx.x * 256 + threadIdx.x;
    if (t < RK * CIN) {
        int r = t >> 5, c = t & 31;
        Ut[t] = Ucin[c * RK + r];
    }
}

// ---- k1d: T1d[r,p] = d-conv(sum_c x[c,p]*Ut[r][c]) via wave shfl ----
// Block = 4 waves; wave = one d-row (lanes 0..55 active).
__global__ __launch_bounds__(256) void k1d(
    const float* __restrict__ x, const float* __restrict__ Ut,
    const float* __restrict__ Ukd, float* __restrict__ T1d)
{
    const int lane = threadIdx.x & 63;          // d index
    const int row  = blockIdx.x * 4 + (threadIdx.x >> 6);   // (h,w) row in [0,3136)
    const int p    = row * 56 + lane;
    const bool act = (lane < 56);

    float xv[CIN];
#pragma unroll
    for (int c = 0; c < CIN; ++c) xv[c] = act ? x[c * NP + p] : 0.f;

#pragma unroll 2
    for (int r = 0; r < RK; ++r) {
        const float* U = Ut + r * CIN;          // uniform -> s_load
        float acc = 0.f;
#pragma unroll
        for (int c = 0; c < CIN; ++c) acc += xv[c] * U[c];
        float lm = __shfl_up(acc, 1, 64);
        float rp = __shfl_down(acc, 1, 64);
        if (lane == 0)  lm = 0.f;
        if (lane == 55) rp = 0.f;
        float res = lm * Ukd[r] + acc * Ukd[RK + r] + rp * Ukd[2 * RK + r];
        if (act) T1d[(size_t)r * NP + p] = res;
    }
}

// ---- k3wh: out[o,q] = sum_r sum_ij kh[i]kw[j] * T1d[r, h+i-1, w+j-1, :] * Ucout[r][o] ----
// float2 lanes: 1372 blocks x 4 waves; wave owns 16 out-channels (og uniform -> s_load).
// Invalid taps: offset forced to 0 (in-bounds center load) and weight masked by 0.
__global__ __launch_bounds__(256, 4) void k3wh(
    const float2* __restrict__ Ta, const float* __restrict__ Ucout,
    const float* __restrict__ bias, const float* __restrict__ Ukh,
    const float* __restrict__ Ukw, float2* __restrict__ Out)
{
    const int lane = threadIdx.x & 63;
    int og = (threadIdx.x >> 6) << 4;            // 0,16,32,48
    og = __builtin_amdgcn_readfirstlane(og);
    const int q = blockIdx.x * 64 + lane;        // float2 column
    const int h = q / H2;
    const int w = (q - h * H2) / W2;

    int   off[9];
    float msk[9];
#pragma unroll
    for (int i = 0; i < 3; ++i)
#pragma unroll
        for (int j = 0; j < 3; ++j) {
            int dh = i - 1, dw = j - 1;
            bool v = ((unsigned)(h + dh) < 56u) && ((unsigned)(w + dw) < 56u);
            off[i * 3 + j] = v ? dh * H2 + dw * W2 : 0;
            msk[i * 3 + j] = v ? 1.f : 0.f;
        }

    float2 a[16];
#pragma unroll
    for (int o = 0; o < 16; ++o) {
        float b = bias[og + o];
        a[o].x = b; a[o].y = b;
    }

#pragma unroll 2
    for (int r = 0; r < RK; ++r) {
        const float2* S = Ta + (size_t)r * NP2 + q;
        const float kh0 = Ukh[r], kh1 = Ukh[RK + r], kh2 = Ukh[2 * RK + r];
        const float kw0 = Ukw[r], kw1 = Ukw[RK + r], kw2 = Ukw[2 * RK + r];
        const float kk[9] = { kh0 * kw0, kh0 * kw1, kh0 * kw2,
                              kh1 * kw0, kh1 * kw1, kh1 * kw2,
                              kh2 * kw0, kh2 * kw1, kh2 * kw2 };
        float2 t; t.x = 0.f; t.y = 0.f;
#pragma unroll
        for (int s = 0; s < 9; ++s) {
            float2 v = S[off[s]];
            float m = kk[s] * msk[s];
            t.x += v.x * m; t.y += v.y * m;
        }
        const float* Ur = Ucout + r * COUT + og;   // uniform -> s_load
#pragma unroll
        for (int o = 0; o < 16; ++o) {
            float u = Ur[o];
            a[o].x += t.x * u; a[o].y += t.y * u;
        }
    }
#pragma unroll
    for (int o = 0; o < 16; ++o)
        Out[(size_t)(og + o) * NP2 + q] = a[o];
}

// ===================== fallback path (R5, known good) =====================

__global__ __launch_bounds__(256) void k1_chunk(
    const float* __restrict__ x, const float* __restrict__ Ucin,
    float* T, int r0, int nr)
{
    __shared__ float sU[11 * CIN];
    const int tid = threadIdx.x;
    for (int t = tid; t < nr * CIN; t += 256) {
        int lr = t >> 5, c = t & 31;
        sU[t] = Ucin[c * RK + (r0 + lr)];
    }
    __syncthreads();
    const int p = blockIdx.x * 256 + tid;
    float xv[CIN];
#pragma unroll
    for (int c = 0; c < CIN; ++c) xv[c] = x[c * NP + p];
#pragma unroll 1
    for (int lr = 0; lr < nr; ++lr) {
        float acc = 0.f;
#pragma unroll
        for (int c = 0; c < CIN; ++c) acc += xv[c] * sU[lr * CIN + c];
        T[(size_t)(SCR + lr) * NP + p] = acc;
    }
}

__global__ __launch_bounds__(256) void k2_chunk(
    const float* __restrict__ Ukh, const float* __restrict__ Ukw,
    const float* __restrict__ Ukd, float* T, int r0)
{
    __shared__ float sIn[5800];
    __shared__ float sA[5600];
    const int lr = blockIdx.z;
    const int r  = r0 + lr;
    const int h0 = blockIdx.x * 8, w0 = blockIdx.y * 8;
    const int tid = threadIdx.x;
    const float kh0 = Ukh[r], kh1 = Ukh[RK + r], kh2 = Ukh[2 * RK + r];
    const float kw0 = Ukw[r], kw1 = Ukw[RK + r], kw2 = Ukw[2 * RK + r];
    const float kd0 = Ukd[r], kd1 = Ukd[RK + r], kd2 = Ukd[2 * RK + r];
    const float* T1r = T + (size_t)(SCR + lr) * NP;

    for (int idx = tid; idx < 5800; idx += 256) {
        int d = idx % 58; int t2 = idx / 58; int ww = t2 % 10; int hh = t2 / 10;
        int gh = h0 + hh - 1, gw = w0 + ww - 1, gd = d - 1;
        float v = 0.f;
        if ((unsigned)gh < 56u && (unsigned)gw < 56u && (unsigned)gd < 56u)
            v = T1r[gh * HSTR + gw * 56 + gd];
        sIn[idx] = v;
    }
    __syncthreads();
    for (int idx = tid; idx < 5600; idx += 256) {
        int d = idx % 56; int t2 = idx / 56; int ww = t2 % 10; int hh = t2 / 10;
        const float* b = &sIn[(hh * 10 + ww) * 58 + d];
        sA[idx] = b[0] * kd0 + b[1] * kd1 + b[2] * kd2;
    }
    __syncthreads();
    const float k00 = kh0 * kw0, k01 = kh0 * kw1, k02 = kh0 * kw2;
    const float k10 = kh1 * kw0, k11 = kh1 * kw1, k12 = kh1 * kw2;
    const float k20 = kh2 * kw0, k21 = kh2 * kw1, k22 = kh2 * kw2;
    for (int idx = tid; idx < 3584; idx += 256) {
        int d = idx % 56; int t2 = idx / 56; int ww = t2 % 8; int hh = t2 / 8;
        const float* a = &sA[(hh * 10 + ww) * 56 + d];
        float acc = a[0]    * k00 + a[56]   * k01 + a[112]  * k02
                  + a[560]  * k10 + a[616]  * k11 + a[672]  * k12
                  + a[1120] * k20 + a[1176] * k21 + a[1232] * k22;
        T[(size_t)r * NP + (h0 + hh) * HSTR + (w0 + ww) * 56 + d] = acc;
    }
}

__global__ __launch_bounds__(256) void k3_out(
    float* T, const float* __restrict__ Ucout, const float* __restrict__ bias)
{
    __shared__ float sUo[RK * COUT];
    __shared__ float sB[COUT];
    const int tid = threadIdx.x;
    for (int t = tid; t < RK * COUT; t += 256) sUo[t] = Ucout[t];
    if (tid < COUT) sB[tid] = bias[tid];
    __syncthreads();
    const int p = blockIdx.x * 256 + tid;
    float acc[COUT];
#pragma unroll
    for (int o = 0; o < COUT; ++o) acc[o] = sB[o];
#pragma unroll 1
    for (int r = 0; r < RK; ++r) {
        float t = T[(size_t)r * NP + p];
        const float* Ur = &sUo[r * COUT];
#pragma unroll
        for (int o = 0; o < COUT; ++o) acc[o] += t * Ur[o];
    }
#pragma unroll
    for (int o = 0; o < COUT; ++o) T[(size_t)o * NP + p] = acc[o];
}

// ===================== launch =====================

extern "C" void kernel_launch(void* const* d_in, const int* in_sizes, int n_in,
                              void* d_out, int out_size, void* d_ws, size_t ws_size,
                              hipStream_t stream)
{
    const float* x     = (const float*)d_in[0];
    const float* Ukh   = (const float*)d_in[1];
    const float* Ukw   = (const float*)d_in[2];
    const float* Ukd   = (const float*)d_in[3];
    const float* Ucin  = (const float*)d_in[4];
    const float* Ucout = (const float*)d_in[5];
    const float* bias  = (const float*)d_in[6];

    const size_t t1_bytes = (size_t)RK * NP * sizeof(float);   // 37.2 MB

    if (ws_size >= t1_bytes + 8192) {
        float* T1 = (float*)d_ws;
        float* Ut = (float*)((char*)d_ws + t1_bytes);          // 6.8 KB
        k0_t<<<7, 256, 0, stream>>>(Ucin, Ut);
        k1d<<<HSTR / 4, 256, 0, stream>>>(x, Ut, Ukd, T1);     // 784 blocks
        k3wh<<<NP2 / 64, 256, 0, stream>>>((const float2*)T1, Ucout, bias,
                                           Ukh, Ukw, (float2*)d_out);
    } else {
        float* T = (float*)d_out;
        for (int r0 = 0; r0 < RK; r0 += 11) {
            int nr = (RK - r0 < 11) ? (RK - r0) : 11;
            k1_chunk<<<NP / 256, 256, 0, stream>>>(x, Ucin, T, r0, nr);
            k2_chunk<<<dim3(7, 7, nr), 256, 0, stream>>>(Ukh, Ukw, Ukd, T, r0);
        }
        k3_out<<<NP / 256, 256, 0, stream>>>(T, Ucout, bias);
    }
}